// Round 1
// baseline (80.064 us; speedup 1.0000x reference)
//
#include <hip/hip_runtime.h>
#include <stdint.h>

#define NB   32768
#define NIN  64
#define NOUT 32
#define KPI  48                 // K slots per input feature (1 id + 45 bases + 2 pad)
#define KTOT (NIN * KPI)        // 3072
// ws layout (bytes)
#define OFF_PMIN 0              // 128*64*4 = 32768
#define OFF_PMAX 32768          // 32768
#define OFF_FEAT 65536          // 64*24*4 = 6144
#define OFF_EB   71680          // 32*4 = 128
#define OFF_CSW  71808          // 3072*32*2 = 196608 (16B aligned)

typedef __bf16 bf16x8 __attribute__((ext_vector_type(8)));
typedef float  f32x4  __attribute__((ext_vector_type(4)));

__device__ __forceinline__ float softplus_f(float x) {
  return fmaxf(x, 0.0f) + log1pf(expf(-fabsf(x)));
}
__device__ __forceinline__ unsigned short f2bf(float f) {
  unsigned int u = __float_as_uint(f);
  u = (u + 0x7FFFu + ((u >> 16) & 1u)) >> 16;
  return (unsigned short)u;
}
__device__ __forceinline__ unsigned int packbf(float a, float b) {
  return (unsigned int)f2bf(a) | ((unsigned int)f2bf(b) << 16);
}

// ---------------- pass 1: per-feature min/max partials ----------------
__global__ __launch_bounds__(256) void k_minmax(const float* __restrict__ X,
                                                float* __restrict__ pmin,
                                                float* __restrict__ pmax) {
  int t = threadIdx.x, i = t & 63, rg = t >> 6;
  float lo = 3.402823466e38f, hi = -3.402823466e38f;
  for (int k = 0; k < NB / 512; ++k) {
    int b = k * 512 + blockIdx.x * 4 + rg;
    float v = X[b * NIN + i];
    lo = fminf(lo, v); hi = fmaxf(hi, v);
  }
  __shared__ float slo[4][64], shi[4][64];
  slo[rg][i] = lo; shi[rg][i] = hi;
  __syncthreads();
  if (t < 64) {
    lo = fminf(fminf(slo[0][t], slo[1][t]), fminf(slo[2][t], slo[3][t]));
    hi = fmaxf(fmaxf(shi[0][t], shi[1][t]), fmaxf(shi[2][t], shi[3][t]));
    pmin[blockIdx.x * 64 + t] = lo;
    pmax[blockIdx.x * 64 + t] = hi;
  }
}

// ---------------- pass 2: per-feature params (knots, inv_h, wavelet) ----------------
__global__ __launch_bounds__(256) void k_feat(const float* __restrict__ pmin,
                                              const float* __restrict__ pmax,
                                              const float* __restrict__ wscale,
                                              const float* __restrict__ wshift,
                                              const float* __restrict__ alpha,
                                              const float* __restrict__ bias,
                                              float* __restrict__ featp,
                                              float* __restrict__ ebias) {
  __shared__ float slo[4][64], shi[4][64];
  int t = threadIdx.x, i = t & 63, cg = t >> 6;
  float lo = 3.402823466e38f, hi = -3.402823466e38f;
  for (int p = cg; p < 128; p += 4) {
    lo = fminf(lo, pmin[p * 64 + i]);
    hi = fmaxf(hi, pmax[p * 64 + i]);
  }
  slo[cg][i] = lo; shi[cg][i] = hi;
  __syncthreads();
  if (t < 64) {
    lo = fminf(fminf(slo[0][t], slo[1][t]), fminf(slo[2][t], slo[3][t]));
    hi = fmaxf(fmaxf(shi[0][t], shi[1][t]), fmaxf(shi[2][t], shi[3][t]));
    if (hi - lo < 1e-8f) { lo = lo - 0.5f; hi = hi + 0.5f; }
    float d = hi - lo;
    float* fp = featp + t * 24;
    // knots exactly as reference: grid[j] = xmin + d * (0.125*clamp(j-3,0,8)); no FMA contraction
    #pragma unroll
    for (int j = 0; j < 15; ++j) {
      int cj = (j < 3) ? 0 : ((j > 11) ? 8 : (j - 3));
      fp[j] = __fadd_rn(lo, __fmul_rn(d, 0.125f * (float)cj));
    }
    fp[15] = 8.0f / d;  // inv_h
    #pragma unroll
    for (int c = 0; c < 4; ++c) {
      float a = softplus_f(wscale[t * 4 + c]) + 1e-6f;
      fp[16 + c] = 1.0f / a;
      fp[20 + c] = wshift[t * 4 + c];
    }
  }
  if (t >= 128 && t < 160) {
    int o = t - 128;
    ebias[o] = softplus_f(alpha[0]) * bias[o];
  }
}

// ---------------- pass 3: folded coefficients, pre-swizzled for MFMA B-frags ----------------
__global__ __launch_bounds__(256) void k_coef(const float* __restrict__ base_v,
                                              const float* __restrict__ base_g,
                                              const float* __restrict__ bsp,
                                              const float* __restrict__ tay,
                                              const float* __restrict__ jac,
                                              const float* __restrict__ che,
                                              const float* __restrict__ fou,
                                              const float* __restrict__ wav,
                                              const float* __restrict__ gains,
                                              const float* __restrict__ alpha,
                                              const float* __restrict__ beta,
                                              const float* __restrict__ mixl,
                                              unsigned short* __restrict__ Csw) {
  int p = blockIdx.x * 256 + threadIdx.x;  // (o,i) pair, 2048 total
  int o = p >> 6, i = p & 63;
  float spa = softplus_f(alpha[0]);
  float spb = softplus_f(beta[0]);
  float spg[6];
  #pragma unroll
  for (int f = 0; f < 6; ++f) spg[f] = softplus_f(gains[f]);
  float m[6], mmax = -3.402823466e38f;
  #pragma unroll
  for (int f = 0; f < 6; ++f) { m[f] = mixl[p * 6 + f] * 0.5f; mmax = fmaxf(mmax, m[f]); }
  float es = 0.f;
  #pragma unroll
  for (int f = 0; f < 6; ++f) { m[f] = expf(m[f] - mmax); es += m[f]; }
  float inv = 1.0f / es;
  float vn = 0.f;
  for (int ii = 0; ii < 64; ++ii) { float vv = base_v[o * 64 + ii]; vn += vv * vv; }
  vn = sqrtf(vn);

  float slot[48];
  slot[0] = spa * base_g[o] * base_v[p] / vn;       // identity path: sp(alpha)*W[o,i]
  float w;
  w = spb * spg[0] * m[0] * inv;
  #pragma unroll
  for (int k = 0; k < 11; ++k) slot[1 + k] = w * bsp[p * 11 + k];
  w = spb * spg[1] * m[1] * inv;
  #pragma unroll
  for (int k = 0; k < 4; ++k)  slot[12 + k] = w * tay[p * 4 + k];
  w = spb * spg[2] * m[2] * inv;
  #pragma unroll
  for (int k = 0; k < 5; ++k)  slot[16 + k] = w * jac[p * 5 + k];
  w = spb * spg[3] * m[3] * inv;
  #pragma unroll
  for (int k = 0; k < 5; ++k)  slot[21 + k] = w * che[p * 5 + k];
  w = spb * spg[4] * m[4] * inv;
  #pragma unroll
  for (int k = 0; k < 16; ++k) slot[26 + k] = w * fou[p * 16 + k];
  w = spb * spg[5] * m[5] * inv;
  #pragma unroll
  for (int k = 0; k < 4; ++k)  slot[42 + k] = w * wav[p * 4 + k];
  slot[46] = 0.f; slot[47] = 0.f;

  // scatter into Csw[step][kgrp][col=o][j]  (B-fragment layout for mfma_f32_16x16x32_bf16)
  #pragma unroll
  for (int k = 0; k < 48; ++k) {
    int kk = i * 48 + k;
    int st = kk >> 5, r = kk & 31;
    int idx = ((st * 4 + (r >> 3)) * 32 + o) * 8 + (r & 7);
    Csw[idx] = f2bf(slot[k]);
  }
}

// ---------------- pass 4: main fused kernel ----------------
__global__ __launch_bounds__(256) void k_main(const float* __restrict__ X,
                                              const unsigned short* __restrict__ Csw,
                                              const float* __restrict__ featp,
                                              const float* __restrict__ ebias,
                                              float* __restrict__ out) {
  __shared__ __align__(16) unsigned short phi[64][200];  // 64 samples x (4 feat * 48 + pad)
  __shared__ float xs[64][65];
  __shared__ float feat[64][24];
  __shared__ float eb[32];

  int t = threadIdx.x;
  int b0 = blockIdx.x * 64;
  for (int idx = t; idx < 64 * 24; idx += 256) feat[idx / 24][idx % 24] = featp[idx];
  if (t < 32) eb[t] = ebias[t];
  #pragma unroll
  for (int k = 0; k < 16; ++k) {
    int idx = k * 256 + t;
    xs[idx >> 6][idx & 63] = X[b0 * 64 + idx];
  }
  __syncthreads();

  int w = t >> 6, lane = t & 63;
  int col = lane & 15, kg = lane >> 4;
  f32x4 acc0 = {0.f, 0.f, 0.f, 0.f};
  f32x4 acc1 = {0.f, 0.f, 0.f, 0.f};
  const unsigned short* phiA = &phi[w * 16 + col][0];

  for (int c = 0; c < 16; ++c) {
    // ---- compute 48-slot Phi for feature i = c*4 + w, sample = lane ----
    int i = c * 4 + w;
    float x = xs[lane][i];
    const float* fp = &feat[i][0];
    float v[48];
    v[0] = x;
    // B-spline (uniform-grid Cox-de Boor; degenerate denominators -> inv 0, exact)
    float g[15];
    #pragma unroll
    for (int j = 0; j < 15; ++j) g[j] = fp[j];
    float ih = fp[15];
    float b[14];
    #pragma unroll
    for (int tt = 0; tt < 13; ++tt) b[tt] = (x >= g[tt] && x < g[tt + 1]) ? 1.0f : 0.0f;
    b[13] = ((x >= g[13] && x < g[14]) || (x == g[14])) ? 1.0f : 0.0f;
    {
      const float i1l[13] = {0,0,0,1,1,1,1,1,1,1,1,0,0};
      const float i1r[13] = {0,0,1,1,1,1,1,1,1,1,0,0,0};
      #pragma unroll
      for (int tt = 0; tt < 13; ++tt)
        b[tt] = (x - g[tt]) * (i1l[tt] * ih) * b[tt] + (g[tt + 2] - x) * (i1r[tt] * ih) * b[tt + 1];
      const float i2l[12] = {0,0,1,0.5f,0.5f,0.5f,0.5f,0.5f,0.5f,0.5f,1,0};
      const float i2r[12] = {0,1,0.5f,0.5f,0.5f,0.5f,0.5f,0.5f,0.5f,1,0,0};
      #pragma unroll
      for (int tt = 0; tt < 12; ++tt)
        b[tt] = (x - g[tt]) * (i2l[tt] * ih) * b[tt] + (g[tt + 3] - x) * (i2r[tt] * ih) * b[tt + 1];
      const float TH = 0.33333333333333f;
      const float i3l[11] = {0,1,0.5f,TH,TH,TH,TH,TH,TH,0.5f,1};
      const float i3r[11] = {1,0.5f,TH,TH,TH,TH,TH,TH,0.5f,1,0};
      #pragma unroll
      for (int tt = 0; tt < 11; ++tt)
        b[tt] = (x - g[tt]) * (i3l[tt] * ih) * b[tt] + (g[tt + 4] - x) * (i3r[tt] * ih) * b[tt + 1];
      #pragma unroll
      for (int k = 0; k < 11; ++k) v[1 + k] = b[k];
    }
    // Taylor
    {
      float x2 = x * x;
      v[12] = 1.0f; v[13] = x; v[14] = x2 * 0.5f; v[15] = x2 * x * (1.0f / 6.0f);
    }
    // Jacobi (a=b=1), normalized-in-recurrence like the reference
    {
      float j0 = 1.0f;
      float j1 = 1.41421356237f * x;
      float j2 = (1.5f * x * j1 - 0.6f * j0) * 0.57735026919f;
      float j3 = (1.6f * x * j2 - 0.685714285714f * j1) * 0.5f;
      float j4 = (1.66666666667f * x * j3 - 0.740740740741f * j2) * 0.44721359550f;
      v[16] = j0; v[17] = j1; v[18] = j2; v[19] = j3; v[20] = j4;
    }
    // Chebyshev
    {
      float xc = __builtin_isfinite(x) ? x : 0.0f;
      xc = fminf(fmaxf(xc, -1e6f), 1e6f);
      float c0 = 1.0f, c1 = xc;
      float c2 = 2.0f * xc * c1 - c0;
      float c3 = 2.0f * xc * c2 - c1;
      float c4 = 2.0f * xc * c3 - c2;
      v[21] = 1.0f; v[22] = c1 * 0.70710678119f; v[23] = c2 * 0.57735026919f;
      v[24] = c3 * 0.5f; v[25] = c4 * 0.44721359550f;
    }
    // Fourier via angle-addition recurrence, scaled 1/sqrt(16)
    {
      float s1, c1;
      sincosf(x, &s1, &c1);
      float ck = c1, sk = s1;
      v[26] = ck * 0.25f; v[34] = sk * 0.25f;
      #pragma unroll
      for (int k = 2; k <= 8; ++k) {
        float cn = ck * c1 - sk * s1;
        float sn = sk * c1 + ck * s1;
        ck = cn; sk = sn;
        v[25 + k] = ck * 0.25f;
        v[33 + k] = sk * 0.25f;
      }
    }
    // Wavelet (Mexican hat)
    {
      #pragma unroll
      for (int ch = 0; ch < 4; ++ch) {
        float u = (x - fp[20 + ch]) * fp[16 + ch];
        float u2 = u * u;
        v[42 + ch] = (u2 - 1.0f) * expf(-0.5f * u2);
      }
    }
    v[46] = 0.0f; v[47] = 0.0f;

    // pack to bf16 and store row
    unsigned int* prow = (unsigned int*)&phi[lane][0];
    #pragma unroll
    for (int j = 0; j < 24; ++j) prow[w * 24 + j] = packbf(v[2 * j], v[2 * j + 1]);
    __syncthreads();

    // ---- MFMA over this chunk's K = 192 (6 steps) ----
    #pragma unroll
    for (int s = 0; s < 6; ++s) {
      bf16x8 a = *reinterpret_cast<const bf16x8*>(phiA + s * 32 + kg * 8);
      const bf16x8* bb = reinterpret_cast<const bf16x8*>(Csw) + (size_t)((c * 6 + s) * 4 + kg) * 32;
      bf16x8 bv0 = bb[col];
      bf16x8 bv1 = bb[col + 16];
      acc0 = __builtin_amdgcn_mfma_f32_16x16x32_bf16(a, bv0, acc0, 0, 0, 0);
      acc1 = __builtin_amdgcn_mfma_f32_16x16x32_bf16(a, bv1, acc1, 0, 0, 0);
    }
    __syncthreads();
  }

  #pragma unroll
  for (int j = 0; j < 4; ++j) {
    int row = b0 + w * 16 + kg * 4 + j;
    out[row * 32 + col]      = acc0[j] + eb[col];
    out[row * 32 + col + 16] = acc1[j] + eb[col + 16];
  }
}

extern "C" void kernel_launch(void* const* d_in, const int* in_sizes, int n_in,
                              void* d_out, int out_size, void* d_ws, size_t ws_size,
                              hipStream_t stream) {
  const float* X   = (const float*)d_in[0];
  const float* bv  = (const float*)d_in[1];
  const float* bg  = (const float*)d_in[2];
  const float* bbi = (const float*)d_in[3];
  const float* bsp = (const float*)d_in[4];
  const float* tay = (const float*)d_in[5];
  const float* jac = (const float*)d_in[6];
  const float* che = (const float*)d_in[7];
  const float* fou = (const float*)d_in[8];
  const float* wav = (const float*)d_in[9];
  const float* wsc = (const float*)d_in[10];
  const float* wsh = (const float*)d_in[11];
  const float* gns = (const float*)d_in[12];
  const float* alp = (const float*)d_in[13];
  const float* bet = (const float*)d_in[14];
  const float* mxl = (const float*)d_in[15];
  float* out = (float*)d_out;

  uint8_t* w = (uint8_t*)d_ws;
  float* pmin  = (float*)(w + OFF_PMIN);
  float* pmax  = (float*)(w + OFF_PMAX);
  float* featp = (float*)(w + OFF_FEAT);
  float* ebias = (float*)(w + OFF_EB);
  unsigned short* Csw = (unsigned short*)(w + OFF_CSW);

  k_minmax<<<128, 256, 0, stream>>>(X, pmin, pmax);
  k_feat<<<1, 256, 0, stream>>>(pmin, pmax, wsc, wsh, alp, bbi, featp, ebias);
  k_coef<<<8, 256, 0, stream>>>(bv, bg, bsp, tay, jac, che, fou, wav, gns, alp, bet, mxl, Csw);
  k_main<<<512, 256, 0, stream>>>(X, Csw, featp, ebias, out);
}

// Round 2
// 63.750 us; speedup vs baseline: 1.2559x; 1.2559x over previous
//
#include <hip/hip_runtime.h>
#include <stdint.h>

#define NB   32768
#define NIN  64
#define NOUT 32
#define KPI  48                 // K slots per input feature (1 id + 45 bases + 2 pad)
#define KTOT (NIN * KPI)        // 3072
// ws layout (bytes)
#define OFF_PMIN 0              // 128*64*4 = 32768
#define OFF_PMAX 32768          // 32768
#define OFF_FEAT 65536          // 64*24*4 = 6144
#define OFF_EB   71680          // 32*4 = 128
#define OFF_CSW  71808          // 3072*32*2 = 196608 (16B aligned)

typedef __bf16 bf16x8 __attribute__((ext_vector_type(8)));
typedef float  f32x4  __attribute__((ext_vector_type(4)));

__device__ __forceinline__ float softplus_f(float x) {
  return fmaxf(x, 0.0f) + log1pf(expf(-fabsf(x)));
}
__device__ __forceinline__ unsigned short f2bf(float f) {
  unsigned int u = __float_as_uint(f);
  u = (u + 0x7FFFu + ((u >> 16) & 1u)) >> 16;
  return (unsigned short)u;
}

// ---------------- pass 1: per-feature min/max partials (float4) ----------------
__global__ __launch_bounds__(256) void k_minmax(const float* __restrict__ X,
                                                float* __restrict__ pmin,
                                                float* __restrict__ pmax) {
  const float4* X4 = (const float4*)X;
  int t = threadIdx.x;
  int g = t & 15, r = t >> 4;
  float4 lo = {3.402823466e38f, 3.402823466e38f, 3.402823466e38f, 3.402823466e38f};
  float4 hi = {-3.402823466e38f, -3.402823466e38f, -3.402823466e38f, -3.402823466e38f};
  int base = blockIdx.x * 4096;  // 256 rows * 16 f4
  #pragma unroll
  for (int k = 0; k < 16; ++k) {
    float4 v = X4[base + k * 256 + t];
    lo.x = fminf(lo.x, v.x); lo.y = fminf(lo.y, v.y);
    lo.z = fminf(lo.z, v.z); lo.w = fminf(lo.w, v.w);
    hi.x = fmaxf(hi.x, v.x); hi.y = fmaxf(hi.y, v.y);
    hi.z = fmaxf(hi.z, v.z); hi.w = fmaxf(hi.w, v.w);
  }
  __shared__ float4 slo[16][16], shi[16][16];
  slo[r][g] = lo; shi[r][g] = hi;
  __syncthreads();
  if (t < 64) {
    int gg = t >> 2, c = t & 3;
    float l = 3.402823466e38f, h = -3.402823466e38f;
    #pragma unroll
    for (int rr = 0; rr < 16; ++rr) {
      const float* pl = (const float*)&slo[rr][gg];
      const float* ph = (const float*)&shi[rr][gg];
      l = fminf(l, pl[c]); h = fmaxf(h, ph[c]);
    }
    pmin[blockIdx.x * 64 + t] = l;
    pmax[blockIdx.x * 64 + t] = h;
  }
}

// ---------------- pass 2: per-feature params (knots, inv_h, wavelet) ----------------
__global__ __launch_bounds__(256) void k_feat(const float* __restrict__ pmin,
                                              const float* __restrict__ pmax,
                                              const float* __restrict__ wscale,
                                              const float* __restrict__ wshift,
                                              const float* __restrict__ alpha,
                                              const float* __restrict__ bias,
                                              float* __restrict__ featp,
                                              float* __restrict__ ebias) {
  __shared__ float slo[4][64], shi[4][64];
  int t = threadIdx.x, i = t & 63, cg = t >> 6;
  float lo = 3.402823466e38f, hi = -3.402823466e38f;
  for (int p = cg; p < 128; p += 4) {
    lo = fminf(lo, pmin[p * 64 + i]);
    hi = fmaxf(hi, pmax[p * 64 + i]);
  }
  slo[cg][i] = lo; shi[cg][i] = hi;
  __syncthreads();
  if (t < 64) {
    lo = fminf(fminf(slo[0][t], slo[1][t]), fminf(slo[2][t], slo[3][t]));
    hi = fmaxf(fmaxf(shi[0][t], shi[1][t]), fmaxf(shi[2][t], shi[3][t]));
    if (hi - lo < 1e-8f) { lo = lo - 0.5f; hi = hi + 0.5f; }
    float d = hi - lo;
    float* fp = featp + t * 24;
    // knots exactly as reference: grid[j] = xmin + d * (0.125*clamp(j-3,0,8)); no FMA contraction
    #pragma unroll
    for (int j = 0; j < 15; ++j) {
      int cj = (j < 3) ? 0 : ((j > 11) ? 8 : (j - 3));
      fp[j] = __fadd_rn(lo, __fmul_rn(d, 0.125f * (float)cj));
    }
    fp[15] = 8.0f / d;  // inv_h
    #pragma unroll
    for (int c = 0; c < 4; ++c) {
      float a = softplus_f(wscale[t * 4 + c]) + 1e-6f;
      fp[16 + c] = 1.0f / a;
      fp[20 + c] = wshift[t * 4 + c];
    }
  }
  if (t >= 128 && t < 160) {
    int o = t - 128;
    ebias[o] = softplus_f(alpha[0]) * bias[o];
  }
}

// ---------------- pass 3: folded coefficients, pre-swizzled for MFMA B-frags ----------------
__global__ __launch_bounds__(64) void k_coef(const float* __restrict__ base_v,
                                             const float* __restrict__ base_g,
                                             const float* __restrict__ bsp,
                                             const float* __restrict__ tay,
                                             const float* __restrict__ jac,
                                             const float* __restrict__ che,
                                             const float* __restrict__ fou,
                                             const float* __restrict__ wav,
                                             const float* __restrict__ gains,
                                             const float* __restrict__ alpha,
                                             const float* __restrict__ beta,
                                             const float* __restrict__ mixl,
                                             unsigned short* __restrict__ Csw) {
  int o = blockIdx.x, i = threadIdx.x;
  int p = o * 64 + i;
  float spa = softplus_f(alpha[0]);
  float spb = softplus_f(beta[0]);
  float spg[6];
  #pragma unroll
  for (int f = 0; f < 6; ++f) spg[f] = softplus_f(gains[f]);
  float m[6], mmax = -3.402823466e38f;
  #pragma unroll
  for (int f = 0; f < 6; ++f) { m[f] = mixl[p * 6 + f] * 0.5f; mmax = fmaxf(mmax, m[f]); }
  float es = 0.f;
  #pragma unroll
  for (int f = 0; f < 6; ++f) { m[f] = __expf(m[f] - mmax); es += m[f]; }
  float inv = 1.0f / es;

  float vv = base_v[p];
  float s2 = vv * vv;
  #pragma unroll
  for (int d = 1; d < 64; d <<= 1) s2 += __shfl_xor(s2, d);
  float vn = sqrtf(s2);

  float slot[48];
  slot[0] = spa * base_g[o] * vv / vn;       // identity path: sp(alpha)*W[o,i]
  float w;
  w = spb * spg[0] * m[0] * inv;
  #pragma unroll
  for (int k = 0; k < 11; ++k) slot[1 + k] = w * bsp[p * 11 + k];
  w = spb * spg[1] * m[1] * inv;
  #pragma unroll
  for (int k = 0; k < 4; ++k)  slot[12 + k] = w * tay[p * 4 + k];
  w = spb * spg[2] * m[2] * inv;
  #pragma unroll
  for (int k = 0; k < 5; ++k)  slot[16 + k] = w * jac[p * 5 + k];
  w = spb * spg[3] * m[3] * inv;
  #pragma unroll
  for (int k = 0; k < 5; ++k)  slot[21 + k] = w * che[p * 5 + k];
  w = spb * spg[4] * m[4] * inv;
  #pragma unroll
  for (int k = 0; k < 16; ++k) slot[26 + k] = w * fou[p * 16 + k];
  w = spb * spg[5] * m[5] * inv;
  #pragma unroll
  for (int k = 0; k < 4; ++k)  slot[42 + k] = w * wav[p * 4 + k];
  slot[46] = 0.f; slot[47] = 0.f;

  // scatter into Csw[step][kgrp][col=o][j]  (B-fragment layout for mfma_f32_16x16x32_bf16)
  #pragma unroll
  for (int k = 0; k < 48; ++k) {
    int kk = i * 48 + k;
    int st = kk >> 5, r = kk & 31;
    int idx = ((st * 4 + (r >> 3)) * 32 + o) * 8 + (r & 7);
    Csw[idx] = f2bf(slot[k]);
  }
}

// ---------------- pass 4: main fused kernel ----------------
__global__ __launch_bounds__(256) void k_main(const float* __restrict__ X,
                                              const unsigned short* __restrict__ Csw,
                                              const float* __restrict__ featp,
                                              const float* __restrict__ ebias,
                                              float* __restrict__ out) {
  __shared__ __align__(16) unsigned short phi[64][200];  // 64 samples x (4 feat * 48 + pad)
  __shared__ float xs[64][65];
  __shared__ float feat[64][24];
  __shared__ float eb[32];

  int t = threadIdx.x;
  int b0 = blockIdx.x * 64;
  for (int idx = t; idx < 64 * 24; idx += 256) feat[idx / 24][idx % 24] = featp[idx];
  if (t < 32) eb[t] = ebias[t];
  #pragma unroll
  for (int k = 0; k < 16; ++k) {
    int idx = k * 256 + t;
    xs[idx >> 6][idx & 63] = X[b0 * 64 + idx];
  }
  __syncthreads();

  int w = t >> 6, lane = t & 63;
  int col = lane & 15, kg = lane >> 4;
  f32x4 acc0 = {0.f, 0.f, 0.f, 0.f};
  f32x4 acc1 = {0.f, 0.f, 0.f, 0.f};
  const unsigned short* phiA = &phi[w * 16 + col][0];

  for (int c = 0; c < 16; ++c) {
    // ---- compute 48-slot Phi for feature i = c*4 + w, sample = lane ----
    int i = c * 4 + w;
    float x = xs[lane][i];
    const float* fp = &feat[i][0];
    float v[48];
    v[0] = x;
    // B-spline (uniform-grid Cox-de Boor; degenerate denominators -> inv 0, exact)
    float g[15];
    #pragma unroll
    for (int j = 0; j < 15; ++j) g[j] = fp[j];
    float ih = fp[15];
    float b[14];
    #pragma unroll
    for (int tt = 0; tt < 13; ++tt) b[tt] = (x >= g[tt] && x < g[tt + 1]) ? 1.0f : 0.0f;
    b[13] = ((x >= g[13] && x < g[14]) || (x == g[14])) ? 1.0f : 0.0f;
    {
      const float i1l[13] = {0,0,0,1,1,1,1,1,1,1,1,0,0};
      const float i1r[13] = {0,0,1,1,1,1,1,1,1,1,0,0,0};
      #pragma unroll
      for (int tt = 0; tt < 13; ++tt)
        b[tt] = (x - g[tt]) * (i1l[tt] * ih) * b[tt] + (g[tt + 2] - x) * (i1r[tt] * ih) * b[tt + 1];
      const float i2l[12] = {0,0,1,0.5f,0.5f,0.5f,0.5f,0.5f,0.5f,0.5f,1,0};
      const float i2r[12] = {0,1,0.5f,0.5f,0.5f,0.5f,0.5f,0.5f,0.5f,1,0,0};
      #pragma unroll
      for (int tt = 0; tt < 12; ++tt)
        b[tt] = (x - g[tt]) * (i2l[tt] * ih) * b[tt] + (g[tt + 3] - x) * (i2r[tt] * ih) * b[tt + 1];
      const float TH = 0.33333333333333f;
      const float i3l[11] = {0,1,0.5f,TH,TH,TH,TH,TH,TH,0.5f,1};
      const float i3r[11] = {1,0.5f,TH,TH,TH,TH,TH,TH,0.5f,1,0};
      #pragma unroll
      for (int tt = 0; tt < 11; ++tt)
        b[tt] = (x - g[tt]) * (i3l[tt] * ih) * b[tt] + (g[tt + 4] - x) * (i3r[tt] * ih) * b[tt + 1];
      #pragma unroll
      for (int k = 0; k < 11; ++k) v[1 + k] = b[k];
    }
    // Taylor
    {
      float x2 = x * x;
      v[12] = 1.0f; v[13] = x; v[14] = x2 * 0.5f; v[15] = x2 * x * (1.0f / 6.0f);
    }
    // Jacobi (a=b=1), normalized-in-recurrence like the reference
    {
      float j0 = 1.0f;
      float j1 = 1.41421356237f * x;
      float j2 = (1.5f * x * j1 - 0.6f * j0) * 0.57735026919f;
      float j3 = (1.6f * x * j2 - 0.685714285714f * j1) * 0.5f;
      float j4 = (1.66666666667f * x * j3 - 0.740740740741f * j2) * 0.44721359550f;
      v[16] = j0; v[17] = j1; v[18] = j2; v[19] = j3; v[20] = j4;
    }
    // Chebyshev
    {
      float xc = __builtin_isfinite(x) ? x : 0.0f;
      xc = fminf(fmaxf(xc, -1e6f), 1e6f);
      float c0 = 1.0f, c1 = xc;
      float c2 = 2.0f * xc * c1 - c0;
      float c3 = 2.0f * xc * c2 - c1;
      float c4 = 2.0f * xc * c3 - c2;
      v[21] = 1.0f; v[22] = c1 * 0.70710678119f; v[23] = c2 * 0.57735026919f;
      v[24] = c3 * 0.5f; v[25] = c4 * 0.44721359550f;
    }
    // Fourier via angle-addition recurrence from NATIVE sin/cos, scaled 1/sqrt(16)
    {
      float s1 = __sinf(x), c1 = __cosf(x);
      float ck = c1, sk = s1;
      v[26] = ck * 0.25f; v[34] = sk * 0.25f;
      #pragma unroll
      for (int k = 2; k <= 8; ++k) {
        float cn = ck * c1 - sk * s1;
        float sn = sk * c1 + ck * s1;
        ck = cn; sk = sn;
        v[25 + k] = ck * 0.25f;
        v[33 + k] = sk * 0.25f;
      }
    }
    // Wavelet (Mexican hat), native exp
    {
      #pragma unroll
      for (int ch = 0; ch < 4; ++ch) {
        float u = (x - fp[20 + ch]) * fp[16 + ch];
        float u2 = u * u;
        v[42 + ch] = (u2 - 1.0f) * __expf(-0.5f * u2);
      }
    }
    v[46] = 0.0f; v[47] = 0.0f;

    // pack to bf16 via vector casts (compiler emits v_cvt_pk_bf16_f32) + b128 stores
    #pragma unroll
    for (int j = 0; j < 6; ++j) {
      bf16x8 pk;
      #pragma unroll
      for (int e = 0; e < 8; ++e) pk[e] = (__bf16)v[j * 8 + e];
      *reinterpret_cast<bf16x8*>(&phi[lane][w * 48 + j * 8]) = pk;
    }
    __syncthreads();

    // ---- MFMA over this chunk's K = 192 (6 steps) ----
    #pragma unroll
    for (int s = 0; s < 6; ++s) {
      bf16x8 a = *reinterpret_cast<const bf16x8*>(phiA + s * 32 + kg * 8);
      const bf16x8* bb = reinterpret_cast<const bf16x8*>(Csw) + (size_t)((c * 6 + s) * 4 + kg) * 32;
      bf16x8 bv0 = bb[col];
      bf16x8 bv1 = bb[col + 16];
      acc0 = __builtin_amdgcn_mfma_f32_16x16x32_bf16(a, bv0, acc0, 0, 0, 0);
      acc1 = __builtin_amdgcn_mfma_f32_16x16x32_bf16(a, bv1, acc1, 0, 0, 0);
    }
    __syncthreads();
  }

  #pragma unroll
  for (int j = 0; j < 4; ++j) {
    int row = b0 + w * 16 + kg * 4 + j;
    out[row * 32 + col]      = acc0[j] + eb[col];
    out[row * 32 + col + 16] = acc1[j] + eb[col + 16];
  }
}

extern "C" void kernel_launch(void* const* d_in, const int* in_sizes, int n_in,
                              void* d_out, int out_size, void* d_ws, size_t ws_size,
                              hipStream_t stream) {
  const float* X   = (const float*)d_in[0];
  const float* bv  = (const float*)d_in[1];
  const float* bg  = (const float*)d_in[2];
  const float* bbi = (const float*)d_in[3];
  const float* bsp = (const float*)d_in[4];
  const float* tay = (const float*)d_in[5];
  const float* jac = (const float*)d_in[6];
  const float* che = (const float*)d_in[7];
  const float* fou = (const float*)d_in[8];
  const float* wav = (const float*)d_in[9];
  const float* wsc = (const float*)d_in[10];
  const float* wsh = (const float*)d_in[11];
  const float* gns = (const float*)d_in[12];
  const float* alp = (const float*)d_in[13];
  const float* bet = (const float*)d_in[14];
  const float* mxl = (const float*)d_in[15];
  float* out = (float*)d_out;

  uint8_t* w = (uint8_t*)d_ws;
  float* pmin  = (float*)(w + OFF_PMIN);
  float* pmax  = (float*)(w + OFF_PMAX);
  float* featp = (float*)(w + OFF_FEAT);
  float* ebias = (float*)(w + OFF_EB);
  unsigned short* Csw = (unsigned short*)(w + OFF_CSW);

  k_minmax<<<128, 256, 0, stream>>>(X, pmin, pmax);
  k_feat<<<1, 256, 0, stream>>>(pmin, pmax, wsc, wsh, alp, bbi, featp, ebias);
  k_coef<<<32, 64, 0, stream>>>(bv, bg, bsp, tay, jac, che, fou, wav, gns, alp, bet, mxl, Csw);
  k_main<<<512, 256, 0, stream>>>(X, Csw, featp, ebias, out);
}

// Round 3
// 58.426 us; speedup vs baseline: 1.3704x; 1.0911x over previous
//
#include <hip/hip_runtime.h>
#include <stdint.h>

#define NB   32768
#define NIN  64
#define NOUT 32
// ws layout (bytes)
#define OFF_PMIN 0          // 128*64*4 = 32768
#define OFF_PMAX 32768      // 32768
#define OFF_FEAT 65536      // 64*12*4 = 3072
#define OFF_EB   68608      // 32*4 = 128
#define OFF_CSW  68736      // 3072*32*2 = 196608 (16B aligned)

typedef __bf16 bf16x8 __attribute__((ext_vector_type(8)));
typedef float  f32x4  __attribute__((ext_vector_type(4)));

__device__ __forceinline__ float softplus_f(float x) {
  return fmaxf(x, 0.0f) + log1pf(expf(-fabsf(x)));
}
__device__ __forceinline__ unsigned short f2bf(float f) {
  unsigned int u = __float_as_uint(f);
  u = (u + 0x7FFFu + ((u >> 16) & 1u)) >> 16;
  return (unsigned short)u;
}

// ---------------- pass 1: per-feature min/max partials (float4) ----------------
__global__ __launch_bounds__(256) void k_minmax(const float* __restrict__ X,
                                                float* __restrict__ pmin,
                                                float* __restrict__ pmax) {
  const float4* X4 = (const float4*)X;
  int t = threadIdx.x;
  int g = t & 15, r = t >> 4;
  float4 lo = {3.402823466e38f, 3.402823466e38f, 3.402823466e38f, 3.402823466e38f};
  float4 hi = {-3.402823466e38f, -3.402823466e38f, -3.402823466e38f, -3.402823466e38f};
  int base = blockIdx.x * 4096;  // 256 rows * 16 f4
  #pragma unroll
  for (int k = 0; k < 16; ++k) {
    float4 v = X4[base + k * 256 + t];
    lo.x = fminf(lo.x, v.x); lo.y = fminf(lo.y, v.y);
    lo.z = fminf(lo.z, v.z); lo.w = fminf(lo.w, v.w);
    hi.x = fmaxf(hi.x, v.x); hi.y = fmaxf(hi.y, v.y);
    hi.z = fmaxf(hi.z, v.z); hi.w = fmaxf(hi.w, v.w);
  }
  __shared__ float4 slo[16][16], shi[16][16];
  slo[r][g] = lo; shi[r][g] = hi;
  __syncthreads();
  if (t < 64) {
    int gg = t >> 2, c = t & 3;
    float l = 3.402823466e38f, h = -3.402823466e38f;
    #pragma unroll
    for (int rr = 0; rr < 16; ++rr) {
      const float* pl = (const float*)&slo[rr][gg];
      const float* ph = (const float*)&shi[rr][gg];
      l = fminf(l, pl[c]); h = fmaxf(h, ph[c]);
    }
    pmin[blockIdx.x * 64 + t] = l;
    pmax[blockIdx.x * 64 + t] = h;
  }
}

// ---------------- pass 2: fused setup: blocks 0-7 = coef, block 8 = feat params ----------------
__global__ __launch_bounds__(256) void k_setup(const float* __restrict__ pmin,
                                               const float* __restrict__ pmax,
                                               const float* __restrict__ wscale,
                                               const float* __restrict__ wshift,
                                               const float* __restrict__ alpha,
                                               const float* __restrict__ bias,
                                               const float* __restrict__ base_v,
                                               const float* __restrict__ base_g,
                                               const float* __restrict__ bsp,
                                               const float* __restrict__ tay,
                                               const float* __restrict__ jac,
                                               const float* __restrict__ che,
                                               const float* __restrict__ fou,
                                               const float* __restrict__ wav,
                                               const float* __restrict__ gains,
                                               const float* __restrict__ beta,
                                               const float* __restrict__ mixl,
                                               float* __restrict__ featp,
                                               float* __restrict__ ebias,
                                               unsigned short* __restrict__ Csw) {
  int t = threadIdx.x;
  if (blockIdx.x < 8) {
    // ---- coef: fold everything into Csw, B-fragment pre-swizzled ----
    int o = blockIdx.x * 4 + (t >> 6);
    int i = t & 63;
    int p = o * 64 + i;
    float spa = softplus_f(alpha[0]);
    float spb = softplus_f(beta[0]);
    float spg[6];
    #pragma unroll
    for (int f = 0; f < 6; ++f) spg[f] = softplus_f(gains[f]);
    float m[6], mmax = -3.402823466e38f;
    #pragma unroll
    for (int f = 0; f < 6; ++f) { m[f] = mixl[p * 6 + f] * 0.5f; mmax = fmaxf(mmax, m[f]); }
    float es = 0.f;
    #pragma unroll
    for (int f = 0; f < 6; ++f) { m[f] = __expf(m[f] - mmax); es += m[f]; }
    float inv = 1.0f / es;

    float vv = base_v[p];
    float s2 = vv * vv;
    #pragma unroll
    for (int d = 1; d < 64; d <<= 1) s2 += __shfl_xor(s2, d);
    float vn = sqrtf(s2);

    float slot[48];
    slot[0] = spa * base_g[o] * vv / vn;   // identity path: sp(alpha)*W[o,i]
    float w;
    w = spb * spg[0] * m[0] * inv;
    #pragma unroll
    for (int k = 0; k < 11; ++k) slot[1 + k] = w * bsp[p * 11 + k];
    w = spb * spg[1] * m[1] * inv;
    #pragma unroll
    for (int k = 0; k < 4; ++k)  slot[12 + k] = w * tay[p * 4 + k];
    w = spb * spg[2] * m[2] * inv;
    #pragma unroll
    for (int k = 0; k < 5; ++k)  slot[16 + k] = w * jac[p * 5 + k];
    w = spb * spg[3] * m[3] * inv;
    #pragma unroll
    for (int k = 0; k < 5; ++k)  slot[21 + k] = w * che[p * 5 + k];
    w = spb * spg[4] * m[4] * inv;
    #pragma unroll
    for (int k = 0; k < 16; ++k) slot[26 + k] = w * fou[p * 16 + k];
    w = spb * spg[5] * m[5] * inv;
    #pragma unroll
    for (int k = 0; k < 4; ++k)  slot[42 + k] = w * wav[p * 4 + k];
    slot[46] = 0.f; slot[47] = 0.f;

    // scatter into Csw[step][kgrp][col=o][j]
    #pragma unroll
    for (int k = 0; k < 48; ++k) {
      int kk = i * 48 + k;
      int st = kk >> 5, r = kk & 31;
      int idx = ((st * 4 + (r >> 3)) * 32 + o) * 8 + (r & 7);
      Csw[idx] = f2bf(slot[k]);
    }
  } else {
    // ---- feat: final min/max reduce + per-feature params ----
    __shared__ float slo[4][64], shi[4][64];
    int i = t & 63, cg = t >> 6;
    float lo = 3.402823466e38f, hi = -3.402823466e38f;
    for (int p = cg; p < 128; p += 4) {
      lo = fminf(lo, pmin[p * 64 + i]);
      hi = fmaxf(hi, pmax[p * 64 + i]);
    }
    slo[cg][i] = lo; shi[cg][i] = hi;
    __syncthreads();
    if (t < 64) {
      lo = fminf(fminf(slo[0][t], slo[1][t]), fminf(slo[2][t], slo[3][t]));
      hi = fmaxf(fmaxf(shi[0][t], shi[1][t]), fmaxf(shi[2][t], shi[3][t]));
      if (hi - lo < 1e-8f) { lo = lo - 0.5f; hi = hi + 0.5f; }
      float d = hi - lo;
      float* fp = featp + t * 12;
      fp[0] = lo;
      fp[1] = 8.0f / d;   // u = (x-lo)*ih maps grid to integers 0..8
      #pragma unroll
      for (int c = 0; c < 4; ++c) {
        float a = softplus_f(wscale[t * 4 + c]) + 1e-6f;
        fp[2 + c] = 1.0f / a;
        fp[6 + c] = wshift[t * 4 + c];
      }
      fp[10] = 0.f; fp[11] = 0.f;
    }
    if (t >= 128 && t < 160) {
      int o = t - 128;
      ebias[o] = softplus_f(alpha[0]) * bias[o];
    }
  }
}

// ---------------- pass 3: main fused kernel (barrier-free waves) ----------------
// 128 threads = 2 waves. Wave w: samples blockIdx*16..+15, features [w*32, w*32+32).
// Each wave: 8 passes x (4 feats basis -> LDS phi -> 6 MFMA K-steps). One final
// __syncthreads for the cross-wave K-reduction.
__global__ __launch_bounds__(128, 3) void k_main(const float* __restrict__ X,
                                                 const unsigned short* __restrict__ Csw,
                                                 const float* __restrict__ featp,
                                                 const float* __restrict__ ebias,
                                                 float* __restrict__ out) {
  __shared__ __align__(16) unsigned short phi[2][16][200];

  int t = threadIdx.x;
  int w = t >> 6, lane = t & 63;
  int s = lane & 15, g = lane >> 4;        // sample-in-block, feature-subgroup
  int col = s, kg = g;                     // MFMA col / k-group aliases
  int sbase = blockIdx.x * 16;

  // preload this lane's 8 x values (cols w*32 + c*4 + g)
  float xr[8];
  #pragma unroll
  for (int c = 0; c < 8; ++c)
    xr[c] = X[(sbase + s) * 64 + w * 32 + c * 4 + g];

  f32x4 acc0 = {0.f, 0.f, 0.f, 0.f};
  f32x4 acc1 = {0.f, 0.f, 0.f, 0.f};
  const unsigned short* phiA = &phi[w][col][0];
  unsigned short* phiW = &phi[w][s][g * 48];
  const bf16x8* CB = reinterpret_cast<const bf16x8*>(Csw);

  #pragma unroll 1
  for (int c = 0; c < 8; ++c) {
    int f = w * 32 + c * 4 + g;
    const float4* fq = (const float4*)(featp + f * 12);
    float4 q0 = fq[0];   // xmin, ih, inva0, inva1
    float4 q1 = fq[1];   // inva2, inva3, shift0, shift1
    float4 q2 = fq[2];   // shift2, shift3, -, -
    float x = xr[c];

    float v[48];
    v[0] = x;

    // ---- B-spline, normalized coords: u in [0,8], integer knots, clamped ends ----
    {
      float u = (x - q0.x) * q0.y;
      int ji = (int)u;                      // floor for u>=0
      float e0 = (ji == 0) ? 1.f : 0.f;
      float e1 = (ji == 1) ? 1.f : 0.f;
      float e2 = (ji == 2) ? 1.f : 0.f;
      float e3 = (ji == 3) ? 1.f : 0.f;
      float e4 = (ji == 4) ? 1.f : 0.f;
      float e5 = (ji == 5) ? 1.f : 0.f;
      float e6 = (ji == 6) ? 1.f : 0.f;
      float e7 = (ji == 7) ? 1.f : 0.f;
      float d0 = u,      d1 = u - 1.f, d2 = u - 2.f, d3 = u - 3.f, d4 = u - 4.f;
      float d5 = u - 5.f, d6 = u - 6.f, d7 = u - 7.f, d8 = u - 8.f;
      // level 1
      float a2 = -d1 * e0;
      float a3 = d0 * e0 - d2 * e1;
      float a4 = d1 * e1 - d3 * e2;
      float a5 = d2 * e2 - d4 * e3;
      float a6 = d3 * e3 - d5 * e4;
      float a7 = d4 * e4 - d6 * e5;
      float a8 = d5 * e5 - d7 * e6;
      float a9 = d6 * e6 - d8 * e7;
      float a10 = d7 * e7;
      // level 2 (half-diffs)
      float h0 = 0.5f * d0, h1 = 0.5f * d1, h2 = 0.5f * d2, h3 = 0.5f * d3, h4 = 0.5f * d4;
      float h5 = 0.5f * d5, h6 = 0.5f * d6, h7 = 0.5f * d7, h8 = 0.5f * d8;
      float c1v = -d1 * a2;
      float c2v = d0 * a2 - h2 * a3;
      float c3v = h0 * a3 - h3 * a4;
      float c4v = h1 * a4 - h4 * a5;
      float c5v = h2 * a5 - h5 * a6;
      float c6v = h3 * a6 - h6 * a7;
      float c7v = h4 * a7 - h7 * a8;
      float c8v = h5 * a8 - h8 * a9;
      float c9v = h6 * a9 - d8 * a10;
      float c10v = d7 * a10;
      // level 3
      const float TH = 0.33333333333333f;
      v[1]  = -d1 * c1v;
      v[2]  = d0 * c1v - h2 * c2v;
      v[3]  = h0 * c2v - TH * (d3 * c3v);
      v[4]  = (d0 * c3v - d4 * c4v) * TH;
      v[5]  = (d1 * c4v - d5 * c5v) * TH;
      v[6]  = (d2 * c5v - d6 * c6v) * TH;
      v[7]  = (d3 * c6v - d7 * c7v) * TH;
      v[8]  = (d4 * c7v - d8 * c8v) * TH;
      v[9]  = TH * (d5 * c8v) - h8 * c9v;
      v[10] = h6 * c9v - d8 * c10v;
      v[11] = d7 * c10v;
    }
    // ---- Taylor ----
    {
      float x2 = x * x;
      v[12] = 1.0f; v[13] = x; v[14] = x2 * 0.5f; v[15] = x2 * x * (1.0f / 6.0f);
    }
    // ---- Jacobi (a=b=1), normalized recurrence ----
    {
      float j0 = 1.0f;
      float j1 = 1.41421356237f * x;
      float j2 = (1.5f * x * j1 - 0.6f * j0) * 0.57735026919f;
      float j3 = (1.6f * x * j2 - 0.685714285714f * j1) * 0.5f;
      float j4 = (1.66666666667f * x * j3 - 0.740740740741f * j2) * 0.44721359550f;
      v[16] = j0; v[17] = j1; v[18] = j2; v[19] = j3; v[20] = j4;
    }
    // ---- Chebyshev ----
    {
      float xc = fminf(fmaxf(x, -1e6f), 1e6f);
      float c0 = 1.0f, cc1 = xc;
      float cc2 = 2.0f * xc * cc1 - c0;
      float cc3 = 2.0f * xc * cc2 - cc1;
      float cc4 = 2.0f * xc * cc3 - cc2;
      v[21] = 1.0f; v[22] = cc1 * 0.70710678119f; v[23] = cc2 * 0.57735026919f;
      v[24] = cc3 * 0.5f; v[25] = cc4 * 0.44721359550f;
    }
    // ---- Fourier via angle-addition from native sin/cos ----
    {
      float s1 = __sinf(x), c1f = __cosf(x);
      float ck = c1f, sk = s1;
      v[26] = ck * 0.25f; v[34] = sk * 0.25f;
      #pragma unroll
      for (int k = 2; k <= 8; ++k) {
        float cn = ck * c1f - sk * s1;
        float sn = sk * c1f + ck * s1;
        ck = cn; sk = sn;
        v[25 + k] = ck * 0.25f;
        v[33 + k] = sk * 0.25f;
      }
    }
    // ---- Wavelet (Mexican hat), native exp ----
    {
      float ia[4] = {q0.z, q0.w, q1.x, q1.y};
      float sh[4] = {q1.z, q1.w, q2.x, q2.y};
      #pragma unroll
      for (int ch = 0; ch < 4; ++ch) {
        float u = (x - sh[ch]) * ia[ch];
        float u2 = u * u;
        v[42 + ch] = (u2 - 1.0f) * __expf(-0.5f * u2);
      }
    }
    v[46] = 0.0f; v[47] = 0.0f;

    // ---- pack to bf16 (v_cvt_pk) + vector LDS stores ----
    #pragma unroll
    for (int j = 0; j < 6; ++j) {
      bf16x8 pk;
      #pragma unroll
      for (int e = 0; e < 8; ++e) pk[e] = (__bf16)v[j * 8 + e];
      *reinterpret_cast<bf16x8*>(phiW + j * 8) = pk;
    }

    // ---- MFMA over this pass's K = 192 (6 steps); wave-internal LDS, no barrier ----
    int st0 = w * 48 + c * 6;
    #pragma unroll
    for (int s6 = 0; s6 < 6; ++s6) {
      bf16x8 a = *reinterpret_cast<const bf16x8*>(phiA + s6 * 32 + kg * 8);
      const bf16x8* bb = CB + (size_t)((st0 + s6) * 4 + kg) * 32;
      acc0 = __builtin_amdgcn_mfma_f32_16x16x32_bf16(a, bb[col], acc0, 0, 0, 0);
      acc1 = __builtin_amdgcn_mfma_f32_16x16x32_bf16(a, bb[col + 16], acc1, 0, 0, 0);
    }
  }

  // ---- cross-wave K-reduction (single barrier) ----
  if (w == 1) {
    float* red = (float*)&phi[1][0][0];
    #pragma unroll
    for (int j = 0; j < 4; ++j) {
      red[(kg * 4 + j) * 32 + col]      = acc0[j];
      red[(kg * 4 + j) * 32 + col + 16] = acc1[j];
    }
  }
  __syncthreads();
  if (w == 0) {
    const float* red = (const float*)&phi[1][0][0];
    float eb0 = ebias[col], eb1 = ebias[col + 16];
    #pragma unroll
    for (int j = 0; j < 4; ++j) {
      int row = sbase + kg * 4 + j;
      out[row * 32 + col]      = acc0[j] + red[(kg * 4 + j) * 32 + col] + eb0;
      out[row * 32 + col + 16] = acc1[j] + red[(kg * 4 + j) * 32 + col + 16] + eb1;
    }
  }
}

extern "C" void kernel_launch(void* const* d_in, const int* in_sizes, int n_in,
                              void* d_out, int out_size, void* d_ws, size_t ws_size,
                              hipStream_t stream) {
  const float* X   = (const float*)d_in[0];
  const float* bv  = (const float*)d_in[1];
  const float* bg  = (const float*)d_in[2];
  const float* bbi = (const float*)d_in[3];
  const float* bsp = (const float*)d_in[4];
  const float* tay = (const float*)d_in[5];
  const float* jac = (const float*)d_in[6];
  const float* che = (const float*)d_in[7];
  const float* fou = (const float*)d_in[8];
  const float* wav = (const float*)d_in[9];
  const float* wsc = (const float*)d_in[10];
  const float* wsh = (const float*)d_in[11];
  const float* gns = (const float*)d_in[12];
  const float* alp = (const float*)d_in[13];
  const float* bet = (const float*)d_in[14];
  const float* mxl = (const float*)d_in[15];
  float* out = (float*)d_out;

  uint8_t* w = (uint8_t*)d_ws;
  float* pmin  = (float*)(w + OFF_PMIN);
  float* pmax  = (float*)(w + OFF_PMAX);
  float* featp = (float*)(w + OFF_FEAT);
  float* ebias = (float*)(w + OFF_EB);
  unsigned short* Csw = (unsigned short*)(w + OFF_CSW);

  k_minmax<<<128, 256, 0, stream>>>(X, pmin, pmax);
  k_setup<<<9, 256, 0, stream>>>(pmin, pmax, wsc, wsh, alp, bbi,
                                 bv, bg, bsp, tay, jac, che, fou, wav,
                                 gns, bet, mxl, featp, ebias, Csw);
  k_main<<<2048, 128, 0, stream>>>(X, Csw, featp, ebias, out);
}

// Round 4
// 47.288 us; speedup vs baseline: 1.6931x; 1.2355x over previous
//
#include <hip/hip_runtime.h>
#include <stdint.h>

#define NB   32768
#define NIN  64
#define NOUT 32
// ws layout (bytes)
#define OFF_PMIN 0          // 128*64*4 = 32768
#define OFF_PMAX 32768      // 32768
#define OFF_FEAT 65536      // 64*12*4 = 3072
#define OFF_EB   68608      // 32*4 = 128
#define OFF_CSW  68736      // 3072*32*2 = 196608 (16B aligned)

typedef __bf16 bf16x8 __attribute__((ext_vector_type(8)));
typedef float  f32x4  __attribute__((ext_vector_type(4)));

__device__ __forceinline__ float softplus_f(float x) {
  return fmaxf(x, 0.0f) + log1pf(expf(-fabsf(x)));
}
__device__ __forceinline__ unsigned short f2bf(float f) {
  unsigned int u = __float_as_uint(f);
  u = (u + 0x7FFFu + ((u >> 16) & 1u)) >> 16;
  return (unsigned short)u;
}

// ---------------- pass 1: per-feature min/max partials (float4) ----------------
__global__ __launch_bounds__(256) void k_minmax(const float* __restrict__ X,
                                                float* __restrict__ pmin,
                                                float* __restrict__ pmax) {
  const float4* X4 = (const float4*)X;
  int t = threadIdx.x;
  int g = t & 15, r = t >> 4;
  float4 lo = {3.402823466e38f, 3.402823466e38f, 3.402823466e38f, 3.402823466e38f};
  float4 hi = {-3.402823466e38f, -3.402823466e38f, -3.402823466e38f, -3.402823466e38f};
  int base = blockIdx.x * 4096;  // 256 rows * 16 f4
  #pragma unroll
  for (int k = 0; k < 16; ++k) {
    float4 v = X4[base + k * 256 + t];
    lo.x = fminf(lo.x, v.x); lo.y = fminf(lo.y, v.y);
    lo.z = fminf(lo.z, v.z); lo.w = fminf(lo.w, v.w);
    hi.x = fmaxf(hi.x, v.x); hi.y = fmaxf(hi.y, v.y);
    hi.z = fmaxf(hi.z, v.z); hi.w = fmaxf(hi.w, v.w);
  }
  __shared__ float4 slo[16][16], shi[16][16];
  slo[r][g] = lo; shi[r][g] = hi;
  __syncthreads();
  if (t < 64) {
    int gg = t >> 2, c = t & 3;
    float l = 3.402823466e38f, h = -3.402823466e38f;
    #pragma unroll
    for (int rr = 0; rr < 16; ++rr) {
      const float* pl = (const float*)&slo[rr][gg];
      const float* ph = (const float*)&shi[rr][gg];
      l = fminf(l, pl[c]); h = fmaxf(h, ph[c]);
    }
    pmin[blockIdx.x * 64 + t] = l;
    pmax[blockIdx.x * 64 + t] = h;
  }
}

// ---------------- pass 2: fused setup: blocks 0-7 = coef, block 8 = feat params ----------------
__global__ __launch_bounds__(256) void k_setup(const float* __restrict__ pmin,
                                               const float* __restrict__ pmax,
                                               const float* __restrict__ wscale,
                                               const float* __restrict__ wshift,
                                               const float* __restrict__ alpha,
                                               const float* __restrict__ bias,
                                               const float* __restrict__ base_v,
                                               const float* __restrict__ base_g,
                                               const float* __restrict__ bsp,
                                               const float* __restrict__ tay,
                                               const float* __restrict__ jac,
                                               const float* __restrict__ che,
                                               const float* __restrict__ fou,
                                               const float* __restrict__ wav,
                                               const float* __restrict__ gains,
                                               const float* __restrict__ beta,
                                               const float* __restrict__ mixl,
                                               float* __restrict__ featp,
                                               float* __restrict__ ebias,
                                               unsigned short* __restrict__ Csw) {
  int t = threadIdx.x;
  if (blockIdx.x < 8) {
    // ---- coef: fold everything into Csw, B-fragment pre-swizzled ----
    int o = blockIdx.x * 4 + (t >> 6);
    int i = t & 63;
    int p = o * 64 + i;
    float spa = softplus_f(alpha[0]);
    float spb = softplus_f(beta[0]);
    float spg[6];
    #pragma unroll
    for (int f = 0; f < 6; ++f) spg[f] = softplus_f(gains[f]);
    float m[6], mmax = -3.402823466e38f;
    #pragma unroll
    for (int f = 0; f < 6; ++f) { m[f] = mixl[p * 6 + f] * 0.5f; mmax = fmaxf(mmax, m[f]); }
    float es = 0.f;
    #pragma unroll
    for (int f = 0; f < 6; ++f) { m[f] = __expf(m[f] - mmax); es += m[f]; }
    float inv = 1.0f / es;

    float vv = base_v[p];
    float s2 = vv * vv;
    #pragma unroll
    for (int d = 1; d < 64; d <<= 1) s2 += __shfl_xor(s2, d);
    float vn = sqrtf(s2);

    float slot[48];
    slot[0] = spa * base_g[o] * vv / vn;   // identity path: sp(alpha)*W[o,i]
    float w;
    w = spb * spg[0] * m[0] * inv;
    #pragma unroll
    for (int k = 0; k < 11; ++k) slot[1 + k] = w * bsp[p * 11 + k];
    w = spb * spg[1] * m[1] * inv;
    #pragma unroll
    for (int k = 0; k < 4; ++k)  slot[12 + k] = w * tay[p * 4 + k];
    w = spb * spg[2] * m[2] * inv;
    #pragma unroll
    for (int k = 0; k < 5; ++k)  slot[16 + k] = w * jac[p * 5 + k];
    w = spb * spg[3] * m[3] * inv;
    #pragma unroll
    for (int k = 0; k < 5; ++k)  slot[21 + k] = w * che[p * 5 + k];
    w = spb * spg[4] * m[4] * inv;
    #pragma unroll
    for (int k = 0; k < 16; ++k) slot[26 + k] = w * fou[p * 16 + k];
    w = spb * spg[5] * m[5] * inv;
    #pragma unroll
    for (int k = 0; k < 4; ++k)  slot[42 + k] = w * wav[p * 4 + k];
    slot[46] = 0.f; slot[47] = 0.f;

    // scatter into Csw[step][kgrp][col=o][j]
    #pragma unroll
    for (int k = 0; k < 48; ++k) {
      int kk = i * 48 + k;
      int st = kk >> 5, r = kk & 31;
      int idx = ((st * 4 + (r >> 3)) * 32 + o) * 8 + (r & 7);
      Csw[idx] = f2bf(slot[k]);
    }
  } else {
    // ---- feat: final min/max reduce + per-feature params ----
    __shared__ float slo[4][64], shi[4][64];
    int i = t & 63, cg = t >> 6;
    float lo = 3.402823466e38f, hi = -3.402823466e38f;
    for (int p = cg; p < 128; p += 4) {
      lo = fminf(lo, pmin[p * 64 + i]);
      hi = fmaxf(hi, pmax[p * 64 + i]);
    }
    slo[cg][i] = lo; shi[cg][i] = hi;
    __syncthreads();
    if (t < 64) {
      lo = fminf(fminf(slo[0][t], slo[1][t]), fminf(slo[2][t], slo[3][t]));
      hi = fmaxf(fmaxf(shi[0][t], shi[1][t]), fmaxf(shi[2][t], shi[3][t]));
      if (hi - lo < 1e-8f) { lo = lo - 0.5f; hi = hi + 0.5f; }
      float d = hi - lo;
      float* fp = featp + t * 12;
      fp[0] = lo;
      fp[1] = 8.0f / d;   // u = (x-lo)*ih maps grid to integers 0..8
      #pragma unroll
      for (int c = 0; c < 4; ++c) {
        float a = softplus_f(wscale[t * 4 + c]) + 1e-6f;
        fp[2 + c] = 1.0f / a;
        fp[6 + c] = wshift[t * 4 + c];
      }
      fp[10] = 0.f; fp[11] = 0.f;
    }
    if (t >= 128 && t < 160) {
      int o = t - 128;
      ebias[o] = softplus_f(alpha[0]) * bias[o];
    }
  }
}

// ---------------- pass 3: main fused kernel ----------------
// 256 threads = 4 waves, all sharing ONE 16-sample tile, K-split 4 ways:
// wave w owns features [w*16, w*16+16) = steps [w*24, w*24+24), runs 4 passes of
// 4 features each with software-pipelined B-fragment prefetch (no barriers),
// then one __syncthreads + 4-way reduction.
__global__ __launch_bounds__(256) void k_main(const float* __restrict__ X,
                                              const unsigned short* __restrict__ Csw,
                                              const float* __restrict__ featp,
                                              const float* __restrict__ ebias,
                                              float* __restrict__ out) {
  __shared__ __align__(16) unsigned short phi[4][16][200];

  int t = threadIdx.x;
  int w = t >> 6, lane = t & 63;
  int col = lane & 15, kg = lane >> 4;   // col = sample-in-tile, kg = feature subgroup / k-group
  int sbase = blockIdx.x * 16;

  // preload this lane's 4 x values (feature = w*16 + c*4 + kg)
  float xr[4];
  #pragma unroll
  for (int c = 0; c < 4; ++c)
    xr[c] = X[(sbase + col) * 64 + w * 16 + c * 4 + kg];

  f32x4 acc0 = {0.f, 0.f, 0.f, 0.f};
  f32x4 acc1 = {0.f, 0.f, 0.f, 0.f};
  const unsigned short* phiA = &phi[w][col][0];
  unsigned short* phiW = &phi[w][col][kg * 48];
  const bf16x8* CB = reinterpret_cast<const bf16x8*>(Csw);
  const bf16x8* CBw = CB + (size_t)w * 3072 + kg * 32;   // frag base: step = w*24, this kg

  // B-fragment register pipeline: 12 frags (6 steps x {col, col+16}) per pass
  bf16x8 B0, B1, B2, B3, B4, B5, B6, B7, B8, B9, B10, B11;
#define LOADB(cc) do { const bf16x8* p_ = CBw + (size_t)(cc) * 768;            \
    B0 = p_[col];        B1 = p_[col + 16];                                    \
    B2 = p_[128 + col];  B3 = p_[128 + col + 16];                              \
    B4 = p_[256 + col];  B5 = p_[256 + col + 16];                              \
    B6 = p_[384 + col];  B7 = p_[384 + col + 16];                              \
    B8 = p_[512 + col];  B9 = p_[512 + col + 16];                              \
    B10 = p_[640 + col]; B11 = p_[640 + col + 16]; } while (0)

  LOADB(0);   // in flight under pass-0 basis compute

  #pragma unroll 1
  for (int c = 0; c < 4; ++c) {
    int f = w * 16 + c * 4 + kg;
    const float4* fq = (const float4*)(featp + f * 12);
    float4 q0 = fq[0];   // xmin, ih, inva0, inva1
    float4 q1 = fq[1];   // inva2, inva3, shift0, shift1
    float4 q2 = fq[2];   // shift2, shift3, -, -
    float x = xr[c];

    float v[48];
    v[0] = x;

    // ---- B-spline, normalized coords: u in [0,8], integer knots, clamped ends ----
    {
      float u = (x - q0.x) * q0.y;
      int ji = (int)u;
      float e0 = (ji == 0) ? 1.f : 0.f;
      float e1 = (ji == 1) ? 1.f : 0.f;
      float e2 = (ji == 2) ? 1.f : 0.f;
      float e3 = (ji == 3) ? 1.f : 0.f;
      float e4 = (ji == 4) ? 1.f : 0.f;
      float e5 = (ji == 5) ? 1.f : 0.f;
      float e6 = (ji == 6) ? 1.f : 0.f;
      float e7 = (ji == 7) ? 1.f : 0.f;
      float d0 = u,       d1 = u - 1.f, d2 = u - 2.f, d3 = u - 3.f, d4 = u - 4.f;
      float d5 = u - 5.f, d6 = u - 6.f, d7 = u - 7.f, d8 = u - 8.f;
      float a2 = -d1 * e0;
      float a3 = d0 * e0 - d2 * e1;
      float a4 = d1 * e1 - d3 * e2;
      float a5 = d2 * e2 - d4 * e3;
      float a6 = d3 * e3 - d5 * e4;
      float a7 = d4 * e4 - d6 * e5;
      float a8 = d5 * e5 - d7 * e6;
      float a9 = d6 * e6 - d8 * e7;
      float a10 = d7 * e7;
      float h0 = 0.5f * d0, h1 = 0.5f * d1, h2 = 0.5f * d2, h3 = 0.5f * d3, h4 = 0.5f * d4;
      float h5 = 0.5f * d5, h6 = 0.5f * d6, h7 = 0.5f * d7, h8 = 0.5f * d8;
      float c1v = -d1 * a2;
      float c2v = d0 * a2 - h2 * a3;
      float c3v = h0 * a3 - h3 * a4;
      float c4v = h1 * a4 - h4 * a5;
      float c5v = h2 * a5 - h5 * a6;
      float c6v = h3 * a6 - h6 * a7;
      float c7v = h4 * a7 - h7 * a8;
      float c8v = h5 * a8 - h8 * a9;
      float c9v = h6 * a9 - d8 * a10;
      float c10v = d7 * a10;
      const float TH = 0.33333333333333f;
      v[1]  = -d1 * c1v;
      v[2]  = d0 * c1v - h2 * c2v;
      v[3]  = h0 * c2v - TH * (d3 * c3v);
      v[4]  = (d0 * c3v - d4 * c4v) * TH;
      v[5]  = (d1 * c4v - d5 * c5v) * TH;
      v[6]  = (d2 * c5v - d6 * c6v) * TH;
      v[7]  = (d3 * c6v - d7 * c7v) * TH;
      v[8]  = (d4 * c7v - d8 * c8v) * TH;
      v[9]  = TH * (d5 * c8v) - h8 * c9v;
      v[10] = h6 * c9v - d8 * c10v;
      v[11] = d7 * c10v;
    }
    // ---- Taylor ----
    {
      float x2 = x * x;
      v[12] = 1.0f; v[13] = x; v[14] = x2 * 0.5f; v[15] = x2 * x * (1.0f / 6.0f);
    }
    // ---- Jacobi (a=b=1), normalized recurrence ----
    {
      float j0 = 1.0f;
      float j1 = 1.41421356237f * x;
      float j2 = (1.5f * x * j1 - 0.6f * j0) * 0.57735026919f;
      float j3 = (1.6f * x * j2 - 0.685714285714f * j1) * 0.5f;
      float j4 = (1.66666666667f * x * j3 - 0.740740740741f * j2) * 0.44721359550f;
      v[16] = j0; v[17] = j1; v[18] = j2; v[19] = j3; v[20] = j4;
    }
    // ---- Chebyshev ----
    {
      float xc = fminf(fmaxf(x, -1e6f), 1e6f);
      float c0 = 1.0f, cc1 = xc;
      float cc2 = 2.0f * xc * cc1 - c0;
      float cc3 = 2.0f * xc * cc2 - cc1;
      float cc4 = 2.0f * xc * cc3 - cc2;
      v[21] = 1.0f; v[22] = cc1 * 0.70710678119f; v[23] = cc2 * 0.57735026919f;
      v[24] = cc3 * 0.5f; v[25] = cc4 * 0.44721359550f;
    }
    // ---- Fourier via angle-addition from native sin/cos ----
    {
      float s1 = __sinf(x), c1f = __cosf(x);
      float ck = c1f, sk = s1;
      v[26] = ck * 0.25f; v[34] = sk * 0.25f;
      #pragma unroll
      for (int k = 2; k <= 8; ++k) {
        float cn = ck * c1f - sk * s1;
        float sn = sk * c1f + ck * s1;
        ck = cn; sk = sn;
        v[25 + k] = ck * 0.25f;
        v[33 + k] = sk * 0.25f;
      }
    }
    // ---- Wavelet (Mexican hat), native exp ----
    {
      float ia[4] = {q0.z, q0.w, q1.x, q1.y};
      float sh[4] = {q1.z, q1.w, q2.x, q2.y};
      #pragma unroll
      for (int ch = 0; ch < 4; ++ch) {
        float u = (x - sh[ch]) * ia[ch];
        float u2 = u * u;
        v[42 + ch] = (u2 - 1.0f) * __expf(-0.5f * u2);
      }
    }
    v[46] = 0.0f; v[47] = 0.0f;

    // ---- pack to bf16 (v_cvt_pk) + vector LDS stores ----
    #pragma unroll
    for (int j = 0; j < 6; ++j) {
      bf16x8 pk;
      #pragma unroll
      for (int e = 0; e < 8; ++e) pk[e] = (__bf16)v[j * 8 + e];
      *reinterpret_cast<bf16x8*>(phiW + j * 8) = pk;
    }

    // ---- MFMA: 6 K-steps, B from registers (prefetched last pass) ----
    {
      bf16x8 a0 = *reinterpret_cast<const bf16x8*>(phiA + 0 * 32 + kg * 8);
      acc0 = __builtin_amdgcn_mfma_f32_16x16x32_bf16(a0, B0, acc0, 0, 0, 0);
      acc1 = __builtin_amdgcn_mfma_f32_16x16x32_bf16(a0, B1, acc1, 0, 0, 0);
      bf16x8 a1 = *reinterpret_cast<const bf16x8*>(phiA + 1 * 32 + kg * 8);
      acc0 = __builtin_amdgcn_mfma_f32_16x16x32_bf16(a1, B2, acc0, 0, 0, 0);
      acc1 = __builtin_amdgcn_mfma_f32_16x16x32_bf16(a1, B3, acc1, 0, 0, 0);
      bf16x8 a2 = *reinterpret_cast<const bf16x8*>(phiA + 2 * 32 + kg * 8);
      acc0 = __builtin_amdgcn_mfma_f32_16x16x32_bf16(a2, B4, acc0, 0, 0, 0);
      acc1 = __builtin_amdgcn_mfma_f32_16x16x32_bf16(a2, B5, acc1, 0, 0, 0);
      bf16x8 a3 = *reinterpret_cast<const bf16x8*>(phiA + 3 * 32 + kg * 8);
      acc0 = __builtin_amdgcn_mfma_f32_16x16x32_bf16(a3, B6, acc0, 0, 0, 0);
      acc1 = __builtin_amdgcn_mfma_f32_16x16x32_bf16(a3, B7, acc1, 0, 0, 0);
      bf16x8 a4 = *reinterpret_cast<const bf16x8*>(phiA + 4 * 32 + kg * 8);
      acc0 = __builtin_amdgcn_mfma_f32_16x16x32_bf16(a4, B8, acc0, 0, 0, 0);
      acc1 = __builtin_amdgcn_mfma_f32_16x16x32_bf16(a4, B9, acc1, 0, 0, 0);
      bf16x8 a5 = *reinterpret_cast<const bf16x8*>(phiA + 5 * 32 + kg * 8);
      acc0 = __builtin_amdgcn_mfma_f32_16x16x32_bf16(a5, B10, acc0, 0, 0, 0);
      acc1 = __builtin_amdgcn_mfma_f32_16x16x32_bf16(a5, B11, acc1, 0, 0, 0);
    }

    // issue next pass's B loads now; they fly under the next basis compute
    if (c < 3) LOADB(c + 1);
  }
#undef LOADB

  // ---- 4-way cross-wave K-reduction (single barrier) ----
  if (w > 0) {
    float* red = (float*)&phi[w][0][0];   // each wave overlays its OWN phi buffer
    #pragma unroll
    for (int j = 0; j < 4; ++j) {
      red[(kg * 4 + j) * 32 + col]      = acc0[j];
      red[(kg * 4 + j) * 32 + col + 16] = acc1[j];
    }
  }
  __syncthreads();
  if (w == 0) {
    const float* r1 = (const float*)&phi[1][0][0];
    const float* r2 = (const float*)&phi[2][0][0];
    const float* r3 = (const float*)&phi[3][0][0];
    float eb0 = ebias[col], eb1 = ebias[col + 16];
    #pragma unroll
    for (int j = 0; j < 4; ++j) {
      int idx0 = (kg * 4 + j) * 32 + col;
      int idx1 = idx0 + 16;
      int row = sbase + kg * 4 + j;
      out[row * 32 + col]      = acc0[j] + r1[idx0] + r2[idx0] + r3[idx0] + eb0;
      out[row * 32 + col + 16] = acc1[j] + r1[idx1] + r2[idx1] + r3[idx1] + eb1;
    }
  }
}

extern "C" void kernel_launch(void* const* d_in, const int* in_sizes, int n_in,
                              void* d_out, int out_size, void* d_ws, size_t ws_size,
                              hipStream_t stream) {
  const float* X   = (const float*)d_in[0];
  const float* bv  = (const float*)d_in[1];
  const float* bg  = (const float*)d_in[2];
  const float* bbi = (const float*)d_in[3];
  const float* bsp = (const float*)d_in[4];
  const float* tay = (const float*)d_in[5];
  const float* jac = (const float*)d_in[6];
  const float* che = (const float*)d_in[7];
  const float* fou = (const float*)d_in[8];
  const float* wav = (const float*)d_in[9];
  const float* wsc = (const float*)d_in[10];
  const float* wsh = (const float*)d_in[11];
  const float* gns = (const float*)d_in[12];
  const float* alp = (const float*)d_in[13];
  const float* bet = (const float*)d_in[14];
  const float* mxl = (const float*)d_in[15];
  float* out = (float*)d_out;

  uint8_t* w = (uint8_t*)d_ws;
  float* pmin  = (float*)(w + OFF_PMIN);
  float* pmax  = (float*)(w + OFF_PMAX);
  float* featp = (float*)(w + OFF_FEAT);
  float* ebias = (float*)(w + OFF_EB);
  unsigned short* Csw = (unsigned short*)(w + OFF_CSW);

  k_minmax<<<128, 256, 0, stream>>>(X, pmin, pmax);
  k_setup<<<9, 256, 0, stream>>>(pmin, pmax, wsc, wsh, alp, bbi,
                                 bv, bg, bsp, tay, jac, che, fou, wav,
                                 gns, bet, mxl, featp, ebias, Csw);
  k_main<<<2048, 256, 0, stream>>>(X, Csw, featp, ebias, out);
}